// Round 1
// baseline (56.741 us; speedup 1.0000x reference)
//
#include <hip/hip_runtime.h>
#include <hip/hip_bf16.h>

// LearnableInterpolation: out[b,t,n] = sum_o softmax_o(-3*(tpos[o,n]-tgt[t])^2) * x[b,o,n]
// B=32, L_org=L_to=2048, N=21.  Softmax over o is a near-delta (exp(-3 d^2),
// tap spacing = ratio in [0.7,1.3]) -> 17-tap window around the peak is exact
// to ~e^-80 relative.  One block per t; weights in LDS; 672 outputs per block.

constexpr int LORG  = 2048;
constexpr int LTO   = 2048;
constexpr int NCH   = 21;
constexpr int BATCH = 32;
constexpr int W     = 8;
constexpr int NW    = 2 * W + 1;   // 17 taps

constexpr float MIN_RATIO = 0.7f, MAX_RATIO = 1.3f;
constexpr float MIN_BIAS  = -4.0f, MAX_BIAS = 4.0f;
constexpr float SM_SCALE  = 3.0f;

__global__ __launch_bounds__(256) void li_kernel(
    const float* __restrict__ x,      // [B, LORG, NCH]
    const float* __restrict__ rmo,    // [NCH]
    const float* __restrict__ bias,   // [NCH]
    float* __restrict__ out)          // [B, LTO, NCH]
{
    const int t   = blockIdx.x;           // 0..LTO-1
    const int tid = threadIdx.x;

    __shared__ float wsh[NCH][NW];
    __shared__ int   osh[NCH];

    if (tid < NCH) {
        const float ratio = fminf(fmaxf(rmo[tid] + 1.0f, MIN_RATIO), MAX_RATIO);
        const float bb    = fminf(fmaxf(bias[tid], MIN_BIAS), MAX_BIAS);
        const float tg    = (float)(t - LTO);                 // tgt value (negative)
        // solve (o - LORG)*ratio + bb == tg  ->  o = LORG + (tg - bb)/ratio
        const float ocf = (float)LORG + (tg - bb) / ratio;
        int o0 = (int)floorf(ocf + 0.5f) - W;
        o0 = max(0, min(LORG - NW, o0));
        osh[tid] = o0;

        float ex[NW];
        float m = -1e30f;
        #pragma unroll
        for (int j = 0; j < NW; ++j) {
            const float tp = (float)(o0 + j - LORG) * ratio + bb;
            const float d  = tp - tg;
            ex[j] = -SM_SCALE * d * d;
            m = fmaxf(m, ex[j]);
        }
        float s = 0.0f;
        #pragma unroll
        for (int j = 0; j < NW; ++j) { ex[j] = __expf(ex[j] - m); s += ex[j]; }
        const float inv = 1.0f / s;
        #pragma unroll
        for (int j = 0; j < NW; ++j) wsh[tid][j] = ex[j] * inv;
    }
    __syncthreads();

    for (int idx = tid; idx < BATCH * NCH; idx += blockDim.x) {
        const int b = idx / NCH;
        const int n = idx - b * NCH;
        const int o0 = osh[n];
        const float* xp = x + ((size_t)b * LORG + o0) * NCH + n;
        float acc = 0.0f;
        #pragma unroll
        for (int j = 0; j < NW; ++j)
            acc = fmaf(wsh[n][j], xp[j * NCH], acc);
        out[((size_t)b * LTO + t) * NCH + n] = acc;
    }
}

extern "C" void kernel_launch(void* const* d_in, const int* in_sizes, int n_in,
                              void* d_out, int out_size, void* d_ws, size_t ws_size,
                              hipStream_t stream) {
    const float* x    = (const float*)d_in[0];
    const float* rmo  = (const float*)d_in[1];
    const float* bias = (const float*)d_in[2];
    float* out = (float*)d_out;

    li_kernel<<<LTO, 256, 0, stream>>>(x, rmo, bias, out);
}

// Round 2
// 21.240 us; speedup vs baseline: 2.6714x; 2.6714x over previous
//
#include <hip/hip_runtime.h>
#include <hip/hip_bf16.h>

// LearnableInterpolation: out[b,t,n] = sum_o softmax_o(-3*(tpos[o,n]-tgt[t])^2) * x[b,o,n]
// B=32, L_org=L_to=2048, N=21. Softmax over o is a near-delta -> 17-tap window.
//
// R2 structure: the R1 kernel was L2-bandwidth/latency bound (23M stride-84B
// scalar loads, each pulling a full 64B line => ~1.5GB L2 traffic ~ 43us).
// Fix: (1) transpose x -> xt[N,B,L] (all coalesced), (2) per (n,b,t-tile)
// block stages the contiguous xt column range in LDS and does LDS FMAs.

constexpr int LORG  = 2048;
constexpr int LTO   = 2048;
constexpr int NCH   = 21;
constexpr int BATCH = 32;
constexpr int W     = 8;
constexpr int NW    = 2 * W + 1;   // 17 taps

constexpr float MIN_RATIO = 0.7f, MAX_RATIO = 1.3f;
constexpr float MIN_BIAS  = -4.0f, MAX_BIAS = 4.0f;
constexpr float SM_SCALE  = 3.0f;

// ---------------- kernel 1: transpose x[B,LORG,NCH] -> xt[NCH,BATCH,LORG] ---
__global__ __launch_bounds__(256) void li_transpose(
    const float* __restrict__ x, float* __restrict__ xt)
{
    const int b  = blockIdx.y;
    const int o0 = blockIdx.x * 64;
    __shared__ float tile[64 * NCH];
    const float* src = x + ((size_t)b * LORG + o0) * NCH;
    for (int i = threadIdx.x; i < 64 * NCH; i += 256) tile[i] = src[i];
    __syncthreads();
    for (int j = threadIdx.x; j < 64 * NCH; j += 256) {
        const int n = j >> 6, k = j & 63;              // lane==k -> coalesced write
        xt[((size_t)(n * BATCH + b)) * LORG + o0 + k] = tile[k * NCH + n];
    }
}

// ---------------- kernel 2: main interpolation ------------------------------
// block = (t-tile=256, b, n); thread = one t. Stage xt[n][b][o_lo..o_hi) in LDS.
__global__ __launch_bounds__(256) void li_interp(
    const float* __restrict__ xt,
    const float* __restrict__ rmo,
    const float* __restrict__ bias,
    float* __restrict__ out)
{
    const int t0  = blockIdx.x * 256;
    const int b   = blockIdx.y;
    const int n   = blockIdx.z;
    const int tid = threadIdx.x;
    const int t   = t0 + tid;

    __shared__ float xs[400];          // max span: ceil(255/0.7)+17 = 382
    __shared__ int   sh_olo, sh_ohi;

    const float ratio = fminf(fmaxf(rmo[n] + 1.0f, MIN_RATIO), MAX_RATIO);
    const float bb    = fminf(fmaxf(bias[n], MIN_BIAS), MAX_BIAS);
    const float tg    = (float)(t - LTO);
    const float ocf   = (float)LORG + (tg - bb) / ratio;
    int o0 = (int)floorf(ocf + 0.5f) - W;
    o0 = max(0, min(LORG - NW, o0));
    if (tid == 0)   sh_olo = o0;       // o0 is monotone nondecreasing in t
    if (tid == 255) sh_ohi = o0;

    float w[NW];
    float m = -1e30f;
    #pragma unroll
    for (int j = 0; j < NW; ++j) {
        const float tp = (float)(o0 + j - LORG) * ratio + bb;
        const float d  = tp - tg;
        w[j] = -SM_SCALE * d * d;
        m = fmaxf(m, w[j]);
    }
    float s = 0.0f;
    #pragma unroll
    for (int j = 0; j < NW; ++j) { w[j] = __expf(w[j] - m); s += w[j]; }
    const float inv = 1.0f / s;

    __syncthreads();
    const int o_lo = sh_olo;
    const int len  = min(400, sh_ohi + NW - o_lo);
    const float* col = xt + ((size_t)(n * BATCH + b)) * LORG;
    for (int i = tid; i < len; i += 256) xs[i] = col[o_lo + i];
    __syncthreads();

    float acc = 0.0f;
    const int base = o0 - o_lo;
    #pragma unroll
    for (int j = 0; j < NW; ++j)
        acc = fmaf(w[j], xs[base + j], acc);
    out[((size_t)b * LTO + t) * NCH + n] = acc * inv;
}

// ---------------- fallback (R1 kernel) if ws too small ----------------------
__global__ __launch_bounds__(256) void li_kernel_fallback(
    const float* __restrict__ x,
    const float* __restrict__ rmo,
    const float* __restrict__ bias,
    float* __restrict__ out)
{
    const int t   = blockIdx.x;
    const int tid = threadIdx.x;
    __shared__ float wsh[NCH][NW];
    __shared__ int   osh[NCH];

    if (tid < NCH) {
        const float ratio = fminf(fmaxf(rmo[tid] + 1.0f, MIN_RATIO), MAX_RATIO);
        const float bb    = fminf(fmaxf(bias[tid], MIN_BIAS), MAX_BIAS);
        const float tg    = (float)(t - LTO);
        const float ocf   = (float)LORG + (tg - bb) / ratio;
        int o0 = (int)floorf(ocf + 0.5f) - W;
        o0 = max(0, min(LORG - NW, o0));
        osh[tid] = o0;
        float ex[NW];
        float m = -1e30f;
        #pragma unroll
        for (int j = 0; j < NW; ++j) {
            const float tp = (float)(o0 + j - LORG) * ratio + bb;
            const float d  = tp - tg;
            ex[j] = -SM_SCALE * d * d;
            m = fmaxf(m, ex[j]);
        }
        float s = 0.0f;
        #pragma unroll
        for (int j = 0; j < NW; ++j) { ex[j] = __expf(ex[j] - m); s += ex[j]; }
        const float inv = 1.0f / s;
        #pragma unroll
        for (int j = 0; j < NW; ++j) wsh[tid][j] = ex[j] * inv;
    }
    __syncthreads();

    for (int idx = tid; idx < BATCH * NCH; idx += blockDim.x) {
        const int b  = idx / NCH;
        const int n  = idx - b * NCH;
        const int o0 = osh[n];
        const float* xp = x + ((size_t)b * LORG + o0) * NCH + n;
        float acc = 0.0f;
        #pragma unroll
        for (int j = 0; j < NW; ++j)
            acc = fmaf(wsh[n][j], xp[j * NCH], acc);
        out[((size_t)b * LTO + t) * NCH + n] = acc;
    }
}

extern "C" void kernel_launch(void* const* d_in, const int* in_sizes, int n_in,
                              void* d_out, int out_size, void* d_ws, size_t ws_size,
                              hipStream_t stream) {
    const float* x    = (const float*)d_in[0];
    const float* rmo  = (const float*)d_in[1];
    const float* bias = (const float*)d_in[2];
    float* out = (float*)d_out;

    const size_t xt_bytes = (size_t)NCH * BATCH * LORG * sizeof(float);
    if (ws_size >= xt_bytes) {
        float* xt = (float*)d_ws;
        li_transpose<<<dim3(LORG / 64, BATCH), 256, 0, stream>>>(x, xt);
        li_interp<<<dim3(LTO / 256, BATCH, NCH), 256, 0, stream>>>(xt, rmo, bias, out);
    } else {
        li_kernel_fallback<<<LTO, 256, 0, stream>>>(x, rmo, bias, out);
    }
}